// Round 1
// baseline (756.344 us; speedup 1.0000x reference)
//
#include <hip/hip_runtime.h>

#define BB 4
#define TT 4096
#define NH 16
#define HK 128
#define PE 64
#define DD 1024      // NH * PE
#define RK 16        // PHI_RANK
#define MD 2048      // MODEL_DIM
#define NC 64        // number of T-chunks
#define CS 64        // chunk size (NC*CS == TT)

// ---------------------------------------------------------------------------
// K1: u[b,t,r] = (per-head-L2-normalized hidden) @ W1     (b*t flat = 16384)
// block = 256 threads = 16 tokens; thread owns one 128-dim head chunk.
// ---------------------------------------------------------------------------
__global__ __launch_bounds__(256) void k1_u(const float* __restrict__ hidden,
                                            const float* __restrict__ W1,
                                            float* __restrict__ u) {
  int tid = threadIdx.x;
  int g = tid >> 4;         // token within block
  int c = tid & 15;         // head chunk within token
  int tk = blockIdx.x * 16 + g;   // flat token index
  const float4* hv = (const float4*)(hidden + (size_t)tk * MD + (size_t)c * 128);
  const float* w1b = W1 + (size_t)(c * 128) * RK;

  float ss = 0.f;
  float acc[RK];
#pragma unroll
  for (int r = 0; r < RK; ++r) acc[r] = 0.f;

  for (int j = 0; j < 32; ++j) {           // 32 float4 = 128 dims of this chunk
    float4 v = hv[j];
    ss += v.x * v.x + v.y * v.y + v.z * v.z + v.w * v.w;
    const float* wr = w1b + (size_t)(j * 4) * RK;
    float e[4] = {v.x, v.y, v.z, v.w};
#pragma unroll
    for (int jj = 0; jj < 4; ++jj) {
#pragma unroll
      for (int r = 0; r < RK; ++r) acc[r] += e[jj] * wr[jj * RK + r];
    }
  }

  float inv = rsqrtf(ss + 1e-6f);          // normalization is linear: apply post-dot
#pragma unroll
  for (int r = 0; r < RK; ++r) acc[r] *= inv;

  // sum partial dots across the 16 chunks of this token (16-lane butterfly)
#pragma unroll
  for (int m = 1; m < 16; m <<= 1) {
#pragma unroll
    for (int r = 0; r < RK; ++r) acc[r] += __shfl_xor(acc[r], m, 64);
  }

  // lane c writes u[tk][c]  (all lanes now hold identical full sums)
  float outv = acc[0];
#pragma unroll
  for (int i = 1; i < RK; ++i) outv = (c == i) ? acc[i] : outv;
  u[(size_t)tk * RK + c] = outv;
}

// phi_raw(t, d) = dot(u[b,t,:], W2[:,d]); t<0 -> 0 (causal conv left padding)
__device__ __forceinline__ float phi_raw(const float* __restrict__ ub, int t,
                                         const float* __restrict__ w2r) {
  if (t < 0) return 0.f;
  const float4* up = (const float4*)(ub + (size_t)t * RK);
  float4 u0 = up[0], u1 = up[1], u2 = up[2], u3 = up[3];
  return u0.x * w2r[0]  + u0.y * w2r[1]  + u0.z * w2r[2]  + u0.w * w2r[3]
       + u1.x * w2r[4]  + u1.y * w2r[5]  + u1.z * w2r[6]  + u1.w * w2r[7]
       + u2.x * w2r[8]  + u2.y * w2r[9]  + u2.z * w2r[10] + u2.w * w2r[11]
       + u3.x * w2r[12] + u3.y * w2r[13] + u3.z * w2r[14] + u3.w * w2r[15];
}

// ---------------------------------------------------------------------------
// K2: per-chunk totals of phi_conv over each CS-length chunk.
// grid = BB*NC*4 blocks x 256 threads; thread owns one d channel.
// ---------------------------------------------------------------------------
__global__ __launch_bounds__(256) void k2_csum(const float* __restrict__ u,
                                               const float* __restrict__ W2,
                                               const float* __restrict__ cw,
                                               float* __restrict__ csum) {
  int tid = threadIdx.x;
  int blk = blockIdx.x;
  int dblk = blk & 3;
  int bc = blk >> 2;               // b*NC + chunk
  int chunk = bc & (NC - 1);
  int b = bc >> 6;
  int d = dblk * 256 + tid;

  float w2r[RK];
#pragma unroll
  for (int r = 0; r < RK; ++r) w2r[r] = W2[r * DD + d];
  float c0 = cw[0 * DD + d], c1 = cw[1 * DD + d];
  float c2 = cw[2 * DD + d], c3 = cw[3 * DD + d];

  const float* ub = u + (size_t)b * TT * RK;
  int t0 = chunk * CS;
  float w0 = phi_raw(ub, t0 - 3, w2r);
  float w1 = phi_raw(ub, t0 - 2, w2r);
  float w2v = phi_raw(ub, t0 - 1, w2r);

  float acc = 0.f;
  for (int i = 0; i < CS; ++i) {
    float pr = phi_raw(ub, t0 + i, w2r);
    float cv = c0 * w0 + c1 * w1 + c2 * w2v + c3 * pr;   // tap j hits input[t-3+j]
    w0 = w1; w1 = w2v; w2v = pr;
    acc += cv;
  }
  csum[(size_t)bc * DD + d] = acc;
}

// ---------------------------------------------------------------------------
// K3: exclusive scan of NC chunk totals per (b,d) channel. 4096 threads.
// ---------------------------------------------------------------------------
__global__ __launch_bounds__(256) void k3_scan(const float* __restrict__ csum,
                                               float* __restrict__ cpre) {
  int idx = blockIdx.x * 256 + threadIdx.x;   // b*DD + d
  int b = idx >> 10;
  int d = idx & (DD - 1);
  float run = 0.f;
  for (int c = 0; c < NC; ++c) {
    size_t o = (size_t)(b * NC + c) * DD + d;
    float v = csum[o];
    cpre[o] = run;
    run += v;
  }
}

// ---------------------------------------------------------------------------
// K4: within-chunk running sum + angle + sincos + RoPE apply + store.
// grid = BB*NC*NH blocks x 64 threads (one pe-lane each).
// ---------------------------------------------------------------------------
__global__ __launch_bounds__(64) void k4_apply(const float* __restrict__ u,
                                               const float* __restrict__ W2,
                                               const float* __restrict__ cw,
                                               const float* __restrict__ cpre,
                                               const float* __restrict__ q,
                                               const float* __restrict__ kk,
                                               float* __restrict__ oq,
                                               float* __restrict__ ok) {
  int p = threadIdx.x;             // 0..63 pe index
  int blk = blockIdx.x;
  int h = blk & 15;
  int bc = blk >> 4;               // b*NC + chunk
  int chunk = bc & (NC - 1);
  int b = bc >> 6;
  int d = h * PE + p;

  float w2r[RK];
#pragma unroll
  for (int r = 0; r < RK; ++r) w2r[r] = W2[r * DD + d];
  float c0 = cw[0 * DD + d], c1 = cw[1 * DD + d];
  float c2 = cw[2 * DD + d], c3 = cw[3 * DD + d];

  // temperature[p] = THETA^(-p/64);  log2(500000) = 18.931568569...
  float temp = exp2f(-(float)p * (18.93156856932417f / 64.f));

  const float* ub = u + (size_t)b * TT * RK;
  float s = cpre[(size_t)bc * DD + d];

  int t0 = chunk * CS;
  float w0 = phi_raw(ub, t0 - 3, w2r);
  float w1 = phi_raw(ub, t0 - 2, w2r);
  float w2v = phi_raw(ub, t0 - 1, w2r);

  int qbase = ((b * TT + t0) * NH + h) * HK + p;
  for (int i = 0; i < CS; ++i) {
    float pr = phi_raw(ub, t0 + i, w2r);
    float cv = c0 * w0 + c1 * w1 + c2 * w2v + c3 * pr;
    w0 = w1; w1 = w2v; w2v = pr;
    s += cv;

    float ang = temp * s;
    float sn, cn;
    __sincosf(ang, &sn, &cn);

    int off = qbase + i * (NH * HK);
    float q0 = q[off], q1 = q[off + PE];
    float k0 = kk[off], k1 = kk[off + PE];
    oq[off]      = q0 * cn - q1 * sn;
    oq[off + PE] = q0 * sn + q1 * cn;
    ok[off]      = k0 * cn - k1 * sn;
    ok[off + PE] = k0 * sn + k1 * cn;
  }
}

extern "C" void kernel_launch(void* const* d_in, const int* in_sizes, int n_in,
                              void* d_out, int out_size, void* d_ws, size_t ws_size,
                              hipStream_t stream) {
  const float* q      = (const float*)d_in[0];
  const float* k      = (const float*)d_in[1];
  const float* hidden = (const float*)d_in[2];
  const float* W1     = (const float*)d_in[3];
  const float* W2     = (const float*)d_in[4];
  const float* convw  = (const float*)d_in[5];
  float* out = (float*)d_out;

  float* u    = (float*)d_ws;                  // BB*TT*RK      = 262144 floats (1 MB)
  float* csum = u + (size_t)BB * TT * RK;      // BB*NC*DD      = 262144 floats (1 MB)
  float* cpre = csum + (size_t)BB * NC * DD;   // BB*NC*DD      = 262144 floats (1 MB)

  k1_u<<<(BB * TT) / 16, 256, 0, stream>>>(hidden, W1, u);
  k2_csum<<<BB * NC * 4, 256, 0, stream>>>(u, W2, convw, csum);
  k3_scan<<<(BB * DD) / 256, 256, 0, stream>>>(csum, cpre);
  k4_apply<<<BB * NC * NH, 64, 0, stream>>>(u, W2, convw, cpre, q, k, out,
                                            out + (size_t)BB * TT * NH * HK);
}